// Round 18
// baseline (100.979 us; speedup 1.0000x reference)
//
#include <hip/hip_runtime.h>

#define NV 30000
#define NB 128
#define NS 512
#define ND 300
#define NC 300
#define CP 304
#define KP 320
#define MASK_NEG -1e9f
#define SQ_EPS 1e-8f

typedef __attribute__((ext_vector_type(4))) float f32x4;
typedef __attribute__((ext_vector_type(8))) __bf16 bf16x8;

__device__ __forceinline__ unsigned int f2bfu(float x){
  unsigned int u = __float_as_uint(x);
  u += 0x7FFFu + ((u >> 16) & 1u);
  return u >> 16;
}
__device__ __forceinline__ unsigned short f2bf(float x){ return (unsigned short)f2bfu(x); }

// pre-swizzle: XOR the 16B-chunk index (bits 3..5 of k) with (row&7).
// MUST match k1f's read-side XOR (rule: swizzle both sides or neither).
__device__ __forceinline__ int swzk(int row, int k){
  return (k & ~0x38) | (((((k >> 3) & 7) ^ (row & 7)) & 7) << 3);
}

__device__ __forceinline__ float bsum512(float v, float* red, int tid){
  red[tid] = v; __syncthreads();
  float s = 0.f;
  if (tid < 64){
    s = red[tid]+red[tid+64]+red[tid+128]+red[tid+192]
      + red[tid+256]+red[tid+320]+red[tid+384]+red[tid+448];
    #pragma unroll
    for (int off = 32; off > 0; off >>= 1) s += __shfl_xor(s, off);
    if (tid == 0) red[0] = s;
  }
  __syncthreads();
  s = red[0];
  __syncthreads();
  return s;
}

__device__ __forceinline__ float bmax512(float v, float* red, int tid){
  red[tid] = v; __syncthreads();
  float s = MASK_NEG;
  if (tid < 64){
    s = red[tid];
    #pragma unroll
    for (int o = 64; o < 512; o += 64) s = fmaxf(s, red[tid+o]);
    #pragma unroll
    for (int off = 32; off > 0; off >>= 1) s = fmaxf(s, __shfl_xor(s, off));
    if (tid == 0) red[0] = s;
  }
  __syncthreads();
  s = red[0];
  __syncthreads();
  return s;
}

// ================= kA: 0..24 Ws^T + zero | 25..44 Z col-slices | 45..49 G1 =================
__global__ __launch_bounds__(512) void kA(
    const float* __restrict__ Ws, const float* __restrict__ Wa,
    const float* __restrict__ ba, const int* __restrict__ aspect,
    const float* __restrict__ embed, const float* __restrict__ gcap,
    const float* __restrict__ Gw, const float* __restrict__ bs,
    unsigned short* __restrict__ WTC, float* __restrict__ ZG,
    float* __restrict__ Z2P, float* __restrict__ TG)
{
  __shared__ __align__(16) char shm[55296];
  int bid = blockIdx.x, tid = threadIdx.x;
  int lane = tid & 63, wid = tid >> 6;
  if (bid < 25){
    float (*t)[65] = (float(*)[65])shm;
    int kt = bid / 5, nt = bid - kt*5;
    #pragma unroll
    for (int i = 0; i < 8; i++){
      int idx = i*512 + tid;
      int r = idx >> 6, c = idx & 63;
      int gk = kt*64 + r, gn = nt*64 + c;
      t[r][c] = (gk < ND && gn < NC) ? Ws[gk*NC + gn] : 0.f;
    }
    __syncthreads();
    #pragma unroll
    for (int i = 0; i < 8; i++){
      int idx = i*512 + tid;
      int n = idx >> 6, k = idx & 63;
      int row = nt*64 + n, gk = kt*64 + k;
      WTC[(size_t)row*KP + swzk(row, gk)] = f2bf(t[k][n]);
    }
    if (bid < 24){
      for (int r = 0; r < 8; r++){
        int row = 320 + bid*8 + r;
        if (tid < KP) WTC[(size_t)row*KP + tid] = 0;
      }
    }
  } else if (bid < 45){
    // Z role: Z = Asp @ Wa + ba, cols nc0..nc0+15
    unsigned short (*ATF)[72] = (unsigned short (*)[72])shm;
    unsigned short (*ldbz)[72] = (unsigned short (*)[72])(shm + 128*144);
    int* toksh = (int*)(shm + 144*144);
    int zb = bid - 25;
    int nc0 = zb * 16;
    if (tid < 128) toksh[tid] = aspect[tid];
    __syncthreads();
    f32x4 accz = {0.f,0.f,0.f,0.f};
    for (int s = 0; s < 5; s++){
      int k0 = s*64;
      #pragma unroll
      for (int i = 0; i < 4; i++){
        int idx = i*512 + tid;               // < 2048 = 128 rows * 16 float4
        int row = idx >> 4, q = idx & 15;
        int gk = k0 + 4*q;
        float4 v = {0.f,0.f,0.f,0.f};
        if (gk < ND) v = *(const float4*)(embed + (size_t)toksh[row]*ND + gk);
        uint2 pk; pk.x = f2bfu(v.x)|(f2bfu(v.y)<<16); pk.y = f2bfu(v.z)|(f2bfu(v.w)<<16);
        *(uint2*)(&ATF[row][4*q]) = pk;
      }
      if (tid < 256){                        // Wa^T slice: 64 d-rows x 4 float4
        int dl = tid >> 2, qq = tid & 3;
        int d = k0 + dl, c = nc0 + 4*qq;
        float4 v = {0.f,0.f,0.f,0.f};
        if (d < ND && c < NC) v = *(const float4*)(Wa + (size_t)d*NC + c);
        ldbz[4*qq+0][dl] = f2bf(v.x);
        ldbz[4*qq+1][dl] = f2bf(v.y);
        ldbz[4*qq+2][dl] = f2bf(v.z);
        ldbz[4*qq+3][dl] = f2bf(v.w);
      }
      __syncthreads();
      #pragma unroll
      for (int kk = 0; kk < 64; kk += 32){
        int kl = kk + (lane >> 4)*8;
        bf16x8 a = *(const bf16x8*)(&ATF[wid*16 + (lane & 15)][kl]);
        bf16x8 b = *(const bf16x8*)(&ldbz[lane & 15][kl]);
        accz = __builtin_amdgcn_mfma_f32_16x16x32_bf16(a, b, accz, 0, 0, 0);
      }
      __syncthreads();
    }
    int zc = nc0 + (lane & 15);
    float bav = (zc < NC) ? ba[zc] : 0.f;
    #pragma unroll
    for (int j = 0; j < 4; j++){
      int row = wid*16 + ((lane >> 4) << 2) + j;
      float zv = (zc < NC) ? (accz[j] + bav) : 0.f;
      ZG[(size_t)row*KP + zc] = zv;
      float p = zv*zv;
      #pragma unroll
      for (int off = 1; off < 16; off <<= 1) p += __shfl_xor(p, off);
      if ((lane & 15) == 0) Z2P[zb*128 + row] = p;
    }
  } else {
    // G1 role: G1 = gtil @ Gw^T cols c0..c0+63 -> TG rows 128..130; +bs row 131
    unsigned short (*Ag)[328] = (unsigned short (*)[328])shm;
    unsigned short (*ldbg)[328] = (unsigned short (*)[328])(shm + 16*656);
    float* red = (float*)(shm + 80*656);
    int gb = bid - 45, c0 = gb*64;
    for (int k = 0; k < 3; k++){
      float g = (tid < NC) ? gcap[k*NC + tid] : 0.f;
      float sq = bsum512(g*g, red, tid);
      float ssv = (sq/(1.f+sq))/sqrtf(sq + SQ_EPS);
      if (tid < 328) Ag[k][tid] = (tid < NC) ? f2bf(g*ssv) : (unsigned short)0;
    }
    for (int r = 3; r < 16; r++) if (tid < 328) Ag[r][tid] = 0;
    #pragma unroll
    for (int i = 0; i < 10; i++){
      int idx = i*512 + tid;                  // < 5120 = 64 rows * 80 float4
      int cl = idx / 80, q = idx - cl*80;
      float4 v = {0.f,0.f,0.f,0.f};
      if (c0 + cl < NC && q < 75) v = *(const float4*)(Gw + (size_t)(c0+cl)*NC + 4*q);
      uint2 pk; pk.x = f2bfu(v.x)|(f2bfu(v.y)<<16); pk.y = f2bfu(v.z)|(f2bfu(v.w)<<16);
      *(uint2*)(&ldbg[cl][4*q]) = pk;
    }
    __syncthreads();
    if (wid < 4){
      f32x4 acc = {0.f,0.f,0.f,0.f};
      #pragma unroll
      for (int kk = 0; kk < KP; kk += 32){
        int kidx = kk + (lane >> 4)*8;
        bf16x8 a = *(const bf16x8*)(&Ag[lane & 15][kidx]);
        bf16x8 b = *(const bf16x8*)(&ldbg[wid*16 + (lane & 15)][kidx]);
        acc = __builtin_amdgcn_mfma_f32_16x16x32_bf16(a, b, acc, 0, 0, 0);
      }
      #pragma unroll
      for (int j = 0; j < 4; j++){
        int r = ((lane >> 4) << 2) + j;
        if (r < 3) TG[(size_t)(128 + r)*KP + c0 + wid*16 + (lane & 15)] = acc[j];
      }
    }
    if (gb == 0 && tid < KP) TG[(size_t)131*KP + tid] = (tid < NC) ? bs[tid] : 0.f;
  }
}

// ================= kB: T = (ss*Z) @ Watt^T, cols c0..c0+15 =================
__global__ __launch_bounds__(512) void kB(
    const float* __restrict__ ZG, const float* __restrict__ Z2P,
    const float* __restrict__ Watt, float* __restrict__ TG)
{
  __shared__ unsigned short ATF[128][72];
  __shared__ unsigned short ldbt[16][72];
  __shared__ float ssb[128];
  int tid = threadIdx.x, lane = tid & 63, wid = tid >> 6;
  int c0 = blockIdx.x * 16;
  if (tid < 128){
    float s = 0.f;
    #pragma unroll
    for (int i = 0; i < 20; i++) s += Z2P[i*128 + tid];
    ssb[tid] = (s/(1.f+s))/sqrtf(s + SQ_EPS);
  }
  __syncthreads();
  f32x4 acct = {0.f,0.f,0.f,0.f};
  for (int s = 0; s < 5; s++){
    int k0 = s*64;
    #pragma unroll
    for (int i = 0; i < 4; i++){
      int idx = i*512 + tid;
      int row = idx >> 4, q = idx & 15;
      float4 v = *(const float4*)(ZG + (size_t)row*KP + k0 + 4*q);
      float sv = ssb[row];
      uint2 pk; pk.x = f2bfu(v.x*sv)|(f2bfu(v.y*sv)<<16); pk.y = f2bfu(v.z*sv)|(f2bfu(v.w*sv)<<16);
      *(uint2*)(&ATF[row][4*q]) = pk;
    }
    if (tid < 256){
      int cl = tid >> 4, q = tid & 15;
      int gc = k0 + 4*q;
      float4 v = {0.f,0.f,0.f,0.f};
      if (c0 + cl < NC && gc < NC) v = *(const float4*)(Watt + (size_t)(c0+cl)*NC + gc);
      uint2 pk; pk.x = f2bfu(v.x)|(f2bfu(v.y)<<16); pk.y = f2bfu(v.z)|(f2bfu(v.w)<<16);
      *(uint2*)(&ldbt[cl][4*q]) = pk;
    }
    __syncthreads();
    #pragma unroll
    for (int kk = 0; kk < 64; kk += 32){
      int kl = kk + (lane >> 4)*8;
      bf16x8 a = *(const bf16x8*)(&ATF[wid*16 + (lane & 15)][kl]);
      bf16x8 b = *(const bf16x8*)(&ldbt[lane & 15][kl]);
      acct = __builtin_amdgcn_mfma_f32_16x16x32_bf16(a, b, acct, 0, 0, 0);
    }
    __syncthreads();
  }
  int cc = c0 + (lane & 15);
  #pragma unroll
  for (int j = 0; j < 4; j++){
    int row = wid*16 + ((lane >> 4) << 2) + j;
    TG[(size_t)row*KP + cc] = acct[j];
  }
}

// ================= kC: [T;G1;bs] @ [Ws;bs]^T -> WTC rows 320..451 (swizzled) + BC =================
__global__ __launch_bounds__(512) void kC(
    const float* __restrict__ TG, const float* __restrict__ Ws,
    const float* __restrict__ bs,
    unsigned short* __restrict__ WTC, float* __restrict__ BC)
{
  __shared__ unsigned short ATF[144][72];
  __shared__ unsigned short ldbw[16][72];
  int tid = threadIdx.x, lane = tid & 63, wid = tid >> 6;
  int wb = blockIdx.x;
  int d0 = wb*16;
  f32x4 aw0 = {0.f,0.f,0.f,0.f}, aw8 = {0.f,0.f,0.f,0.f};
  for (int s = 0; s < 5; s++){
    int k0 = s*64;
    #pragma unroll
    for (int i = 0; i < 5; i++){
      int idx = i*512 + tid;
      if (idx < 2304){                     // 144 rows x 16 float4
        int row = idx >> 4, q = idx & 15;
        float4 v = {0.f,0.f,0.f,0.f};
        if (row < 132) v = *(const float4*)(TG + (size_t)row*KP + k0 + 4*q);
        uint2 pk; pk.x = f2bfu(v.x)|(f2bfu(v.y)<<16); pk.y = f2bfu(v.z)|(f2bfu(v.w)<<16);
        *(uint2*)(&ATF[row][4*q]) = pk;
      }
    }
    if (tid < 256){
      int dl = tid >> 4, q = tid & 15;
      int gc = k0 + 4*q;
      float4 v = {0.f,0.f,0.f,0.f};
      if (gc < NC){
        if (wb < 20){ if (d0 + dl < ND) v = *(const float4*)(Ws + (size_t)(d0+dl)*NC + gc); }
        else if (dl == 0) v = *(const float4*)(bs + gc);
      }
      uint2 pk; pk.x = f2bfu(v.x)|(f2bfu(v.y)<<16); pk.y = f2bfu(v.z)|(f2bfu(v.w)<<16);
      *(uint2*)(&ldbw[dl][4*q]) = pk;
    }
    __syncthreads();
    #pragma unroll
    for (int kk = 0; kk < 64; kk += 32){
      int kl = kk + (lane >> 4)*8;
      bf16x8 b = *(const bf16x8*)(&ldbw[lane & 15][kl]);
      bf16x8 a = *(const bf16x8*)(&ATF[wid*16 + (lane & 15)][kl]);
      aw0 = __builtin_amdgcn_mfma_f32_16x16x32_bf16(a, b, aw0, 0, 0, 0);
      bf16x8 a8 = *(const bf16x8*)(&ATF[128 + (lane & 15)][kl]);
      aw8 = __builtin_amdgcn_mfma_f32_16x16x32_bf16(a8, b, aw8, 0, 0, 0);
    }
    __syncthreads();
  }
  int gd = lane & 15;
  #pragma unroll
  for (int j = 0; j < 4; j++){
    int row = wid*16 + ((lane >> 4) << 2) + j;
    if (wb < 20){
      int col = d0 + gd;
      if (col < ND) WTC[(size_t)(320 + row)*KP + swzk(320 + row, col)] = f2bf(aw0[j]);
    } else if (gd == 0) BC[row] = aw0[j];
    if (wid == 0){
      int row8 = 128 + ((lane >> 4) << 2) + j;
      if (row8 < 132){
        if (wb < 20){
          int col = d0 + gd;
          if (col < ND) WTC[(size_t)(320 + row8)*KP + swzk(320 + row8, col)] = f2bf(aw8[j]);
        } else if (gd == 0) BC[row8] = aw8[j];
      }
    }
  }
}

// ================= K1F: embed[30000x320] @ WTC[512x320]^T (WTC pre-swizzled) =================
// BM=64 + LDS-staged epilogue + global_load_lds(16B) B-staging (no VGPR round-trip).
// cols 0..319 -> e.e only; 320..447 -> EtT (f32); 448..451 -> ETS {g0,g1,g2,ebs}
#define LDK 72
__global__ __launch_bounds__(512, 4) void k1f(
    const float* __restrict__ embed, const unsigned short* __restrict__ WTC,
    float* __restrict__ EtT, float* __restrict__ ETS)
{
  __shared__ unsigned short lds_a[64*LDK];
  __shared__ unsigned short lds_b[512*64];   // pre-swizzled chunks; reused as store-stage
  __shared__ float e2part[3][64];
  int tid = threadIdx.x, lane = tid & 63, wid = tid >> 6;
  int wrow = wid >> 2, wcol = wid & 3;
  int rowbase = blockIdx.x * 64;
  f32x4 acc[2][8];
  f32x4 zero = {0.f,0.f,0.f,0.f};
  #pragma unroll
  for (int m = 0; m < 2; m++)
    #pragma unroll
    for (int n = 0; n < 8; n++) acc[m][n] = zero;

  float4 pa[2];
  auto loadA = [&](int k0){
    #pragma unroll
    for (int r = 0; r < 2; r++){
      int id = r*512 + tid;
      int row = id >> 4, k4 = (id & 15) << 2;
      int grow = rowbase + row, gk = k0 + k4;
      float4 v = {0.f,0.f,0.f,0.f};
      if (grow < NV && gk < ND) v = *(const float4*)(embed + (size_t)grow*ND + gk);
      pa[r] = v;
    }
  };
  auto writeA = [&](){
    #pragma unroll
    for (int r = 0; r < 2; r++){
      int id = r*512 + tid;
      int row = id >> 4, k4 = (id & 15) << 2;
      uint2 pk;
      pk.x = f2bfu(pa[r].x) | (f2bfu(pa[r].y) << 16);
      pk.y = f2bfu(pa[r].z) | (f2bfu(pa[r].w) << 16);
      *(uint2*)(lds_a + row*LDK + k4) = pk;
    }
  };
  // B-staging via direct global->LDS DMA: LDS dest = wave-uniform base + lane*16 (id*16),
  // global source per-lane; WTC pre-swizzled so LDS layout stays linear.
  auto stageB = [&](int k0){
    #pragma unroll
    for (int r = 0; r < 8; r++){
      int id = r*512 + tid;
      const unsigned short* gsrc = WTC + (size_t)(id >> 3)*KP + k0 + (id & 7)*8;
      __builtin_amdgcn_global_load_lds(
        (const __attribute__((address_space(1))) unsigned int*)gsrc,
        (__attribute__((address_space(3))) unsigned int*)((char*)lds_b + id*16),
        16, 0, 0);
    }
  };

  loadA(0);
  writeA();
  stageB(0);
  loadA(64);
  __syncthreads();
  for (int step = 0; step < 5; step++){
    #pragma unroll
    for (int kk = 0; kk < 64; kk += 32){
      int kidx = kk + (lane >> 4)*8;
      bf16x8 af[2];
      #pragma unroll
      for (int m = 0; m < 2; m++)
        af[m] = *(const bf16x8*)(lds_a + (wrow*32 + (lane & 15) + m*16)*LDK + kidx);
      #pragma unroll
      for (int n = 0; n < 8; n++){
        int jrow = wcol*128 + n*16 + (lane & 15);
        int ch = ((kidx >> 3) & 7) ^ (jrow & 7);
        bf16x8 bv = *(const bf16x8*)((const char*)lds_b + jrow*128 + ch*16);
        #pragma unroll
        for (int m = 0; m < 2; m++)
          acc[m][n] = __builtin_amdgcn_mfma_f32_16x16x32_bf16(af[m], bv, acc[m][n], 0, 0, 0);
      }
    }
    __syncthreads();
    if (step < 4){
      stageB((step+1)*64);     // async DMA issue first (covers under writeA/loadA)
      writeA();
      if (step < 3) loadA((step+2)*64);
      __syncthreads();
    }
  }

  // -------- LDS-staged epilogue: lds_b is free (last MFMA consumed + barrier) --------
  float* etile = (float*)lds_b;                 // [64][128] f32 = 32 KB
  float* stile = (float*)((char*)lds_b + 32768);// [64][8]  f32 = 2 KB
  int rloc = wrow*32 + ((lane >> 4) << 2);
  #pragma unroll
  for (int m = 0; m < 2; m++)
    #pragma unroll
    for (int n = 0; n < 8; n++){
      int col = wcol*128 + n*16 + (lane & 15);
      #pragma unroll
      for (int j = 0; j < 4; j++){
        int rl = rloc + m*16 + j;
        if (col >= 320 && col < 448)      etile[rl*128 + (col - 320)] = acc[m][n][j];
        else if (col >= 448 && col < 452) stile[rl*8 + (col - 448)] = acc[m][n][j];
      }
    }
  // e.e partials (unchanged reduction chain)
  #pragma unroll
  for (int m = 0; m < 2; m++)
    #pragma unroll
    for (int j = 0; j < 4; j++){
      float p = 0.f;
      #pragma unroll
      for (int n = 0; n < 8; n++)
        if (wcol*128 + n*16 < 320){ float t = acc[m][n][j]; p += t*t; }
      #pragma unroll
      for (int off = 1; off < 16; off <<= 1) p += __shfl_xor(p, off);
      if ((lane & 15) == 0 && wcol < 3) e2part[wcol][rloc + m*16 + j] = p;
    }
  __syncthreads();
  if (tid < 64){
    stile[tid*8 + 4] = e2part[0][tid] + e2part[1][tid] + e2part[2][tid];
    stile[tid*8 + 5] = 0.f; stile[tid*8 + 6] = 0.f; stile[tid*8 + 7] = 0.f;
  }
  __syncthreads();
  // coalesced contiguous copy-out (EtT rows are dense: tile = linear 32 KB span)
  int nrow = NV - rowbase; if (nrow > 64) nrow = 64;
  float4* edst = (float4*)(EtT + (size_t)rowbase*128);
  const float4* esrc = (const float4*)etile;
  int e4 = nrow*32;
  for (int i = tid; i < e4; i += 512) edst[i] = esrc[i];
  float4* sdst = (float4*)(ETS + (size_t)rowbase*8);
  const float4* ssrc = (const float4*)stile;
  int s4 = nrow*2;
  for (int i = tid; i < s4; i += 512) sdst[i] = ssrc[i];
}

// ================= K45: stats+softmax+gather+PROJECT(@Ws)+norm, one block per b =================
__global__ __launch_bounds__(512) void k45(
    const int* __restrict__ sentence, const float* __restrict__ alpha,
    const float* __restrict__ scale_p, const float* __restrict__ embed,
    const float* __restrict__ EtT, const float* __restrict__ ETS,
    const float* __restrict__ BC, const float* __restrict__ bs,
    const float* __restrict__ Ws, float* __restrict__ out)
{
  int b = blockIdx.x;
  int tid = threadIdx.x, lane = tid & 63, w = tid >> 6;
  __shared__ float red[512];
  __shared__ float cfs[NS*3];
  __shared__ int toksh[NS];
  __shared__ float cap8[8][3][CP];
  __shared__ float Qs[3][CP];

  int idx = (b << 9) + tid;
  int tok = sentence[idx];
  float al = alpha[idx];
  toksh[tid] = tok;
  float et = EtT[(size_t)tok*128 + b];
  float4 eg = *(const float4*)(ETS + (size_t)tok*8);   // g0,g1,g2,ebs
  float e2 = ETS[(size_t)tok*8 + 4];
  float bst = BC[b];
  float bsg0 = BC[128], bsg1 = BC[129], bsg2 = BC[130], bs2 = BC[131];

  float sq = al*al*e2 + 2.f*al*eg.w + bs2;
  float ssv = (sq/(1.f+sq))/sqrtf(sq + SQ_EPS);
  float scv = (tok != 0) ? ssv*(al*et + bst) : MASK_NEG;
  float u0 = ssv*(al*eg.x + bsg0);
  float u1 = ssv*(al*eg.y + bsg1);
  float u2 = ssv*(al*eg.z + bsg2);

  float m = bmax512(scv, red, tid);
  float e = expf(scv - m);
  float Z = bsum512(e, red, tid);
  float nw = e / Z;
  float mk = fmaxf(u0, fmaxf(u1, u2));
  float e0 = expf(u0-mk), e1 = expf(u1-mk), e2k = expf(u2-mk);
  float wf = nw * scale_p[0] / (e0+e1+e2k);
  float w0 = e0*wf, w1 = e1*wf, w2 = e2k*wf;
  float ca = ssv * al;
  cfs[tid*3+0] = w0*ca; cfs[tid*3+1] = w1*ca; cfs[tid*3+2] = w2*ca;
  float sb0 = bsum512(w0*ssv, red, tid);
  float sb1 = bsum512(w1*ssv, red, tid);
  float sb2 = bsum512(w2*ssv, red, tid);
  __syncthreads();

  // gather phase: wave w handles tokens [w*64, w*64+64) in EMBEDDING space (D=300)
  f32x4 A0 = {0.f,0.f,0.f,0.f}, A1 = A0, A2 = A0, R0 = A0, R1 = A0, R2 = A0;
  int c0 = lane << 2;
  int c1 = 256 + (lane << 2);
  bool rem = lane < 11;
  int base = w << 6;
  #pragma unroll 4
  for (int i = 0; i < 64; i++){
    int s = base + i;
    int t = toksh[s];
    const float* er = embed + (size_t)t*ND;
    float4 y = *(const float4*)(er + c0);
    float cf0 = cfs[s*3+0], cf1 = cfs[s*3+1], cf2 = cfs[s*3+2];
    f32x4 yv = {y.x, y.y, y.z, y.w};
    A0 += cf0*yv; A1 += cf1*yv; A2 += cf2*yv;
    if (rem){
      float4 y2 = *(const float4*)(er + c1);
      f32x4 y2v = {y2.x, y2.y, y2.z, y2.w};
      R0 += cf0*y2v; R1 += cf1*y2v; R2 += cf2*y2v;
    }
  }
  *(f32x4*)&cap8[w][0][c0] = A0;
  *(f32x4*)&cap8[w][1][c0] = A1;
  *(f32x4*)&cap8[w][2][c0] = A2;
  if (rem){
    *(f32x4*)&cap8[w][0][c1] = R0;
    *(f32x4*)&cap8[w][1][c1] = R1;
    *(f32x4*)&cap8[w][2][c1] = R2;
  }
  __syncthreads();
  // reduce 8 waves -> Qs[k][d] (D-space; no bs term -- projection comes first)
  for (int p = tid; p < 3*CP; p += 512){
    int k = p / CP, c = p - k*CP;
    float v = 0.f;
    if (c < 300){
      #pragma unroll
      for (int w8 = 0; w8 < 8; w8++) v += cap8[w8][k][c];
    }
    Qs[k][c] = v;
  }
  __syncthreads();
  // projection: cap[k][c] = sum_d Ws[d][c]*Qs[k][d] + sb_k*bs[c]  (k45b's exact loop)
  float v0 = 0.f, v1 = 0.f, v2 = 0.f;
  if (tid < NC){
    float a0=0.f,a1=0.f,a2=0.f,b0=0.f,b1=0.f,b2=0.f;
    for (int d = 0; d < 300; d += 2){
      float wA = Ws[d*NC + tid], wB = Ws[(d+1)*NC + tid];
      a0 += wA*Qs[0][d]; b0 += wB*Qs[0][d+1];
      a1 += wA*Qs[1][d]; b1 += wB*Qs[1][d+1];
      a2 += wA*Qs[2][d]; b2 += wB*Qs[2][d+1];
    }
    float bc = bs[tid];
    v0 = a0+b0 + sb0*bc;
    v1 = a1+b1 + sb1*bc;
    v2 = a2+b2 + sb2*bc;
  }
  float s0 = bsum512(v0*v0, red, tid);
  float s1 = bsum512(v1*v1, red, tid);
  float s2 = bsum512(v2*v2, red, tid);
  if (tid == 0){
    out[b*3+0] = (s0/(1.f+s0))*sqrtf(s0)/sqrtf(s0 + SQ_EPS);
    out[b*3+1] = (s1/(1.f+s1))*sqrtf(s1)/sqrtf(s1 + SQ_EPS);
    out[b*3+2] = (s2/(1.f+s2))*sqrtf(s2)/sqrtf(s2 + SQ_EPS);
  }
}

extern "C" void kernel_launch(void* const* d_in, const int* in_sizes, int n_in,
                              void* d_out, int out_size, void* d_ws, size_t ws_size,
                              hipStream_t stream)
{
  (void)in_sizes; (void)n_in; (void)out_size; (void)ws_size;
  const int*   sentence = (const int*)d_in[0];
  const int*   aspect   = (const int*)d_in[1];
  const float* alpha    = (const float*)d_in[2];
  const float* embed    = (const float*)d_in[3];
  const float* Ws       = (const float*)d_in[4];
  const float* bs       = (const float*)d_in[5];
  const float* Wa       = (const float*)d_in[6];
  const float* ba       = (const float*)d_in[7];
  const float* Watt     = (const float*)d_in[8];
  const float* gcap     = (const float*)d_in[9];
  const float* gw       = (const float*)d_in[10];
  const float* scale    = (const float*)d_in[11];
  float* out = (float*)d_out;

  char* w = (char*)d_ws;
  auto alloc = [&](size_t bytes)->char*{
    char* p = w; w += (bytes + 255) & ~(size_t)255; return p;
  };
  unsigned short* WTC = (unsigned short*)alloc((size_t)512*KP*2);
  float* ZG  = (float*)alloc((size_t)128*KP*4);
  float* Z2P = (float*)alloc((size_t)20*128*4);
  float* TG  = (float*)alloc((size_t)132*KP*4);
  float* BC  = (float*)alloc(136*4);
  float* ETT = (float*)alloc((size_t)NV*128*4);
  float* ETS = (float*)alloc((size_t)NV*8*4);

  kA<<<50, 512, 0, stream>>>(Ws, Wa, ba, aspect, embed, gcap, gw, bs, WTC, ZG, Z2P, TG);
  kB<<<20, 512, 0, stream>>>(ZG, Z2P, Watt, TG);
  kC<<<21, 512, 0, stream>>>(TG, Ws, bs, WTC, BC);
  k1f<<<(NV + 63)/64, 512, 0, stream>>>(embed, WTC, ETT, ETS);
  k45<<<NB, 512, 0, stream>>>(sentence, alpha, scale, embed, ETT, ETS, BC, bs, Ws, out);
}

// Round 19
// 91.718 us; speedup vs baseline: 1.1010x; 1.1010x over previous
//
#include <hip/hip_runtime.h>

#define NV 30000
#define NB 128
#define NS 512
#define ND 300
#define NC 300
#define CP 304
#define KP 320
#define MASK_NEG -1e9f
#define SQ_EPS 1e-8f

typedef __attribute__((ext_vector_type(4))) float f32x4;
typedef __attribute__((ext_vector_type(8))) __bf16 bf16x8;

__device__ __forceinline__ unsigned int f2bfu(float x){
  unsigned int u = __float_as_uint(x);
  u += 0x7FFFu + ((u >> 16) & 1u);
  return u >> 16;
}
__device__ __forceinline__ unsigned short f2bf(float x){ return (unsigned short)f2bfu(x); }

// pre-swizzle: XOR the 16B-chunk index (bits 3..5 of k) with (row&7).
// MUST match k1f's read-side XOR (rule: swizzle both sides or neither).
__device__ __forceinline__ int swzk(int row, int k){
  return (k & ~0x38) | (((((k >> 3) & 7) ^ (row & 7)) & 7) << 3);
}

__device__ __forceinline__ float bsum512(float v, float* red, int tid){
  red[tid] = v; __syncthreads();
  float s = 0.f;
  if (tid < 64){
    s = red[tid]+red[tid+64]+red[tid+128]+red[tid+192]
      + red[tid+256]+red[tid+320]+red[tid+384]+red[tid+448];
    #pragma unroll
    for (int off = 32; off > 0; off >>= 1) s += __shfl_xor(s, off);
    if (tid == 0) red[0] = s;
  }
  __syncthreads();
  s = red[0];
  __syncthreads();
  return s;
}

__device__ __forceinline__ float bmax512(float v, float* red, int tid){
  red[tid] = v; __syncthreads();
  float s = MASK_NEG;
  if (tid < 64){
    s = red[tid];
    #pragma unroll
    for (int o = 64; o < 512; o += 64) s = fmaxf(s, red[tid+o]);
    #pragma unroll
    for (int off = 32; off > 0; off >>= 1) s = fmaxf(s, __shfl_xor(s, off));
    if (tid == 0) red[0] = s;
  }
  __syncthreads();
  s = red[0];
  __syncthreads();
  return s;
}

// ================= kA: 0..24 Ws^T + zero | 25..44 Z col-slices | 45..49 G1 =================
__global__ __launch_bounds__(512) void kA(
    const float* __restrict__ Ws, const float* __restrict__ Wa,
    const float* __restrict__ ba, const int* __restrict__ aspect,
    const float* __restrict__ embed, const float* __restrict__ gcap,
    const float* __restrict__ Gw, const float* __restrict__ bs,
    unsigned short* __restrict__ WTC, float* __restrict__ ZG,
    float* __restrict__ Z2P, float* __restrict__ TG)
{
  __shared__ __align__(16) char shm[55296];
  int bid = blockIdx.x, tid = threadIdx.x;
  int lane = tid & 63, wid = tid >> 6;
  if (bid < 25){
    float (*t)[65] = (float(*)[65])shm;
    int kt = bid / 5, nt = bid - kt*5;
    #pragma unroll
    for (int i = 0; i < 8; i++){
      int idx = i*512 + tid;
      int r = idx >> 6, c = idx & 63;
      int gk = kt*64 + r, gn = nt*64 + c;
      t[r][c] = (gk < ND && gn < NC) ? Ws[gk*NC + gn] : 0.f;
    }
    __syncthreads();
    #pragma unroll
    for (int i = 0; i < 8; i++){
      int idx = i*512 + tid;
      int n = idx >> 6, k = idx & 63;
      int row = nt*64 + n, gk = kt*64 + k;
      WTC[(size_t)row*KP + swzk(row, gk)] = f2bf(t[k][n]);
    }
    if (bid < 24){
      for (int r = 0; r < 8; r++){
        int row = 320 + bid*8 + r;
        if (tid < KP) WTC[(size_t)row*KP + tid] = 0;
      }
    }
  } else if (bid < 45){
    // Z role: Z = Asp @ Wa + ba, cols nc0..nc0+15
    unsigned short (*ATF)[72] = (unsigned short (*)[72])shm;
    unsigned short (*ldbz)[72] = (unsigned short (*)[72])(shm + 128*144);
    int* toksh = (int*)(shm + 144*144);
    int zb = bid - 25;
    int nc0 = zb * 16;
    if (tid < 128) toksh[tid] = aspect[tid];
    __syncthreads();
    f32x4 accz = {0.f,0.f,0.f,0.f};
    for (int s = 0; s < 5; s++){
      int k0 = s*64;
      #pragma unroll
      for (int i = 0; i < 4; i++){
        int idx = i*512 + tid;               // < 2048 = 128 rows * 16 float4
        int row = idx >> 4, q = idx & 15;
        int gk = k0 + 4*q;
        float4 v = {0.f,0.f,0.f,0.f};
        if (gk < ND) v = *(const float4*)(embed + (size_t)toksh[row]*ND + gk);
        uint2 pk; pk.x = f2bfu(v.x)|(f2bfu(v.y)<<16); pk.y = f2bfu(v.z)|(f2bfu(v.w)<<16);
        *(uint2*)(&ATF[row][4*q]) = pk;
      }
      if (tid < 256){                        // Wa^T slice: 64 d-rows x 4 float4
        int dl = tid >> 2, qq = tid & 3;
        int d = k0 + dl, c = nc0 + 4*qq;
        float4 v = {0.f,0.f,0.f,0.f};
        if (d < ND && c < NC) v = *(const float4*)(Wa + (size_t)d*NC + c);
        ldbz[4*qq+0][dl] = f2bf(v.x);
        ldbz[4*qq+1][dl] = f2bf(v.y);
        ldbz[4*qq+2][dl] = f2bf(v.z);
        ldbz[4*qq+3][dl] = f2bf(v.w);
      }
      __syncthreads();
      #pragma unroll
      for (int kk = 0; kk < 64; kk += 32){
        int kl = kk + (lane >> 4)*8;
        bf16x8 a = *(const bf16x8*)(&ATF[wid*16 + (lane & 15)][kl]);
        bf16x8 b = *(const bf16x8*)(&ldbz[lane & 15][kl]);
        accz = __builtin_amdgcn_mfma_f32_16x16x32_bf16(a, b, accz, 0, 0, 0);
      }
      __syncthreads();
    }
    int zc = nc0 + (lane & 15);
    float bav = (zc < NC) ? ba[zc] : 0.f;
    #pragma unroll
    for (int j = 0; j < 4; j++){
      int row = wid*16 + ((lane >> 4) << 2) + j;
      float zv = (zc < NC) ? (accz[j] + bav) : 0.f;
      ZG[(size_t)row*KP + zc] = zv;
      float p = zv*zv;
      #pragma unroll
      for (int off = 1; off < 16; off <<= 1) p += __shfl_xor(p, off);
      if ((lane & 15) == 0) Z2P[zb*128 + row] = p;
    }
  } else {
    // G1 role: G1 = gtil @ Gw^T cols c0..c0+63 -> TG rows 128..130; +bs row 131
    unsigned short (*Ag)[328] = (unsigned short (*)[328])shm;
    unsigned short (*ldbg)[328] = (unsigned short (*)[328])(shm + 16*656);
    float* red = (float*)(shm + 80*656);
    int gb = bid - 45, c0 = gb*64;
    for (int k = 0; k < 3; k++){
      float g = (tid < NC) ? gcap[k*NC + tid] : 0.f;
      float sq = bsum512(g*g, red, tid);
      float ssv = (sq/(1.f+sq))/sqrtf(sq + SQ_EPS);
      if (tid < 328) Ag[k][tid] = (tid < NC) ? f2bf(g*ssv) : (unsigned short)0;
    }
    for (int r = 3; r < 16; r++) if (tid < 328) Ag[r][tid] = 0;
    #pragma unroll
    for (int i = 0; i < 10; i++){
      int idx = i*512 + tid;                  // < 5120 = 64 rows * 80 float4
      int cl = idx / 80, q = idx - cl*80;
      float4 v = {0.f,0.f,0.f,0.f};
      if (c0 + cl < NC && q < 75) v = *(const float4*)(Gw + (size_t)(c0+cl)*NC + 4*q);
      uint2 pk; pk.x = f2bfu(v.x)|(f2bfu(v.y)<<16); pk.y = f2bfu(v.z)|(f2bfu(v.w)<<16);
      *(uint2*)(&ldbg[cl][4*q]) = pk;
    }
    __syncthreads();
    if (wid < 4){
      f32x4 acc = {0.f,0.f,0.f,0.f};
      #pragma unroll
      for (int kk = 0; kk < KP; kk += 32){
        int kidx = kk + (lane >> 4)*8;
        bf16x8 a = *(const bf16x8*)(&Ag[lane & 15][kidx]);
        bf16x8 b = *(const bf16x8*)(&ldbg[wid*16 + (lane & 15)][kidx]);
        acc = __builtin_amdgcn_mfma_f32_16x16x32_bf16(a, b, acc, 0, 0, 0);
      }
      #pragma unroll
      for (int j = 0; j < 4; j++){
        int r = ((lane >> 4) << 2) + j;
        if (r < 3) TG[(size_t)(128 + r)*KP + c0 + wid*16 + (lane & 15)] = acc[j];
      }
    }
    if (gb == 0 && tid < KP) TG[(size_t)131*KP + tid] = (tid < NC) ? bs[tid] : 0.f;
  }
}

// ================= kB: T = (ss*Z) @ Watt^T, cols c0..c0+15 =================
__global__ __launch_bounds__(512) void kB(
    const float* __restrict__ ZG, const float* __restrict__ Z2P,
    const float* __restrict__ Watt, float* __restrict__ TG)
{
  __shared__ unsigned short ATF[128][72];
  __shared__ unsigned short ldbt[16][72];
  __shared__ float ssb[128];
  int tid = threadIdx.x, lane = tid & 63, wid = tid >> 6;
  int c0 = blockIdx.x * 16;
  if (tid < 128){
    float s = 0.f;
    #pragma unroll
    for (int i = 0; i < 20; i++) s += Z2P[i*128 + tid];
    ssb[tid] = (s/(1.f+s))/sqrtf(s + SQ_EPS);
  }
  __syncthreads();
  f32x4 acct = {0.f,0.f,0.f,0.f};
  for (int s = 0; s < 5; s++){
    int k0 = s*64;
    #pragma unroll
    for (int i = 0; i < 4; i++){
      int idx = i*512 + tid;
      int row = idx >> 4, q = idx & 15;
      float4 v = *(const float4*)(ZG + (size_t)row*KP + k0 + 4*q);
      float sv = ssb[row];
      uint2 pk; pk.x = f2bfu(v.x*sv)|(f2bfu(v.y*sv)<<16); pk.y = f2bfu(v.z*sv)|(f2bfu(v.w*sv)<<16);
      *(uint2*)(&ATF[row][4*q]) = pk;
    }
    if (tid < 256){
      int cl = tid >> 4, q = tid & 15;
      int gc = k0 + 4*q;
      float4 v = {0.f,0.f,0.f,0.f};
      if (c0 + cl < NC && gc < NC) v = *(const float4*)(Watt + (size_t)(c0+cl)*NC + gc);
      uint2 pk; pk.x = f2bfu(v.x)|(f2bfu(v.y)<<16); pk.y = f2bfu(v.z)|(f2bfu(v.w)<<16);
      *(uint2*)(&ldbt[cl][4*q]) = pk;
    }
    __syncthreads();
    #pragma unroll
    for (int kk = 0; kk < 64; kk += 32){
      int kl = kk + (lane >> 4)*8;
      bf16x8 a = *(const bf16x8*)(&ATF[wid*16 + (lane & 15)][kl]);
      bf16x8 b = *(const bf16x8*)(&ldbt[lane & 15][kl]);
      acct = __builtin_amdgcn_mfma_f32_16x16x32_bf16(a, b, acct, 0, 0, 0);
    }
    __syncthreads();
  }
  int cc = c0 + (lane & 15);
  #pragma unroll
  for (int j = 0; j < 4; j++){
    int row = wid*16 + ((lane >> 4) << 2) + j;
    TG[(size_t)row*KP + cc] = acct[j];
  }
}

// ================= kC: [T;G1;bs] @ [Ws;bs]^T -> WTC rows 320..451 (swizzled) + BC =================
__global__ __launch_bounds__(512) void kC(
    const float* __restrict__ TG, const float* __restrict__ Ws,
    const float* __restrict__ bs,
    unsigned short* __restrict__ WTC, float* __restrict__ BC)
{
  __shared__ unsigned short ATF[144][72];
  __shared__ unsigned short ldbw[16][72];
  int tid = threadIdx.x, lane = tid & 63, wid = tid >> 6;
  int wb = blockIdx.x;
  int d0 = wb*16;
  f32x4 aw0 = {0.f,0.f,0.f,0.f}, aw8 = {0.f,0.f,0.f,0.f};
  for (int s = 0; s < 5; s++){
    int k0 = s*64;
    #pragma unroll
    for (int i = 0; i < 5; i++){
      int idx = i*512 + tid;
      if (idx < 2304){                     // 144 rows x 16 float4
        int row = idx >> 4, q = idx & 15;
        float4 v = {0.f,0.f,0.f,0.f};
        if (row < 132) v = *(const float4*)(TG + (size_t)row*KP + k0 + 4*q);
        uint2 pk; pk.x = f2bfu(v.x)|(f2bfu(v.y)<<16); pk.y = f2bfu(v.z)|(f2bfu(v.w)<<16);
        *(uint2*)(&ATF[row][4*q]) = pk;
      }
    }
    if (tid < 256){
      int dl = tid >> 4, q = tid & 15;
      int gc = k0 + 4*q;
      float4 v = {0.f,0.f,0.f,0.f};
      if (gc < NC){
        if (wb < 20){ if (d0 + dl < ND) v = *(const float4*)(Ws + (size_t)(d0+dl)*NC + gc); }
        else if (dl == 0) v = *(const float4*)(bs + gc);
      }
      uint2 pk; pk.x = f2bfu(v.x)|(f2bfu(v.y)<<16); pk.y = f2bfu(v.z)|(f2bfu(v.w)<<16);
      *(uint2*)(&ldbw[dl][4*q]) = pk;
    }
    __syncthreads();
    #pragma unroll
    for (int kk = 0; kk < 64; kk += 32){
      int kl = kk + (lane >> 4)*8;
      bf16x8 b = *(const bf16x8*)(&ldbw[lane & 15][kl]);
      bf16x8 a = *(const bf16x8*)(&ATF[wid*16 + (lane & 15)][kl]);
      aw0 = __builtin_amdgcn_mfma_f32_16x16x32_bf16(a, b, aw0, 0, 0, 0);
      bf16x8 a8 = *(const bf16x8*)(&ATF[128 + (lane & 15)][kl]);
      aw8 = __builtin_amdgcn_mfma_f32_16x16x32_bf16(a8, b, aw8, 0, 0, 0);
    }
    __syncthreads();
  }
  int gd = lane & 15;
  #pragma unroll
  for (int j = 0; j < 4; j++){
    int row = wid*16 + ((lane >> 4) << 2) + j;
    if (wb < 20){
      int col = d0 + gd;
      if (col < ND) WTC[(size_t)(320 + row)*KP + swzk(320 + row, col)] = f2bf(aw0[j]);
    } else if (gd == 0) BC[row] = aw0[j];
    if (wid == 0){
      int row8 = 128 + ((lane >> 4) << 2) + j;
      if (row8 < 132){
        if (wb < 20){
          int col = d0 + gd;
          if (col < ND) WTC[(size_t)(320 + row8)*KP + swzk(320 + row8, col)] = f2bf(aw8[j]);
        } else if (gd == 0) BC[row8] = aw8[j];
      }
    }
  }
}

// ================= K1F: embed[30000x320] @ WTC[512x320]^T (WTC pre-swizzled) =================
// BM=64 + LDS-staged epilogue + global_load_lds(16B) B-staging (no VGPR round-trip).
// cols 0..319 -> e.e only; 320..447 -> EtT (f32); 448..451 -> ETS {g0,g1,g2,ebs}
#define LDK 72
__global__ __launch_bounds__(512, 4) void k1f(
    const float* __restrict__ embed, const unsigned short* __restrict__ WTC,
    float* __restrict__ EtT, float* __restrict__ ETS)
{
  __shared__ unsigned short lds_a[64*LDK];
  __shared__ unsigned short lds_b[512*64];   // pre-swizzled chunks; reused as store-stage
  __shared__ float e2part[3][64];
  int tid = threadIdx.x, lane = tid & 63, wid = tid >> 6;
  int wrow = wid >> 2, wcol = wid & 3;
  int rowbase = blockIdx.x * 64;
  f32x4 acc[2][8];
  f32x4 zero = {0.f,0.f,0.f,0.f};
  #pragma unroll
  for (int m = 0; m < 2; m++)
    #pragma unroll
    for (int n = 0; n < 8; n++) acc[m][n] = zero;

  float4 pa[2];
  auto loadA = [&](int k0){
    #pragma unroll
    for (int r = 0; r < 2; r++){
      int id = r*512 + tid;
      int row = id >> 4, k4 = (id & 15) << 2;
      int grow = rowbase + row, gk = k0 + k4;
      float4 v = {0.f,0.f,0.f,0.f};
      if (grow < NV && gk < ND) v = *(const float4*)(embed + (size_t)grow*ND + gk);
      pa[r] = v;
    }
  };
  auto writeA = [&](){
    #pragma unroll
    for (int r = 0; r < 2; r++){
      int id = r*512 + tid;
      int row = id >> 4, k4 = (id & 15) << 2;
      uint2 pk;
      pk.x = f2bfu(pa[r].x) | (f2bfu(pa[r].y) << 16);
      pk.y = f2bfu(pa[r].z) | (f2bfu(pa[r].w) << 16);
      *(uint2*)(lds_a + row*LDK + k4) = pk;
    }
  };
  // B-staging via direct global->LDS DMA: LDS dest = wave-uniform base + lane*16 (id*16),
  // global source per-lane; WTC pre-swizzled so LDS layout stays linear.
  auto stageB = [&](int k0){
    #pragma unroll
    for (int r = 0; r < 8; r++){
      int id = r*512 + tid;
      const unsigned short* gsrc = WTC + (size_t)(id >> 3)*KP + k0 + (id & 7)*8;
      __builtin_amdgcn_global_load_lds(
        (const __attribute__((address_space(1))) unsigned int*)gsrc,
        (__attribute__((address_space(3))) unsigned int*)((char*)lds_b + id*16),
        16, 0, 0);
    }
  };

  loadA(0);
  writeA();
  stageB(0);
  loadA(64);
  __syncthreads();
  for (int step = 0; step < 5; step++){
    #pragma unroll
    for (int kk = 0; kk < 64; kk += 32){
      int kidx = kk + (lane >> 4)*8;
      bf16x8 af[2];
      #pragma unroll
      for (int m = 0; m < 2; m++)
        af[m] = *(const bf16x8*)(lds_a + (wrow*32 + (lane & 15) + m*16)*LDK + kidx);
      #pragma unroll
      for (int n = 0; n < 8; n++){
        int jrow = wcol*128 + n*16 + (lane & 15);
        int ch = ((kidx >> 3) & 7) ^ (jrow & 7);
        bf16x8 bv = *(const bf16x8*)((const char*)lds_b + jrow*128 + ch*16);
        #pragma unroll
        for (int m = 0; m < 2; m++)
          acc[m][n] = __builtin_amdgcn_mfma_f32_16x16x32_bf16(af[m], bv, acc[m][n], 0, 0, 0);
      }
    }
    __syncthreads();
    if (step < 4){
      stageB((step+1)*64);     // async DMA issue first (covers under writeA/loadA)
      writeA();
      if (step < 3) loadA((step+2)*64);
      __syncthreads();
    }
  }

  // -------- LDS-staged epilogue: lds_b is free (last MFMA consumed + barrier) --------
  float* etile = (float*)lds_b;                 // [64][128] f32 = 32 KB
  float* stile = (float*)((char*)lds_b + 32768);// [64][8]  f32 = 2 KB
  int rloc = wrow*32 + ((lane >> 4) << 2);
  #pragma unroll
  for (int m = 0; m < 2; m++)
    #pragma unroll
    for (int n = 0; n < 8; n++){
      int col = wcol*128 + n*16 + (lane & 15);
      #pragma unroll
      for (int j = 0; j < 4; j++){
        int rl = rloc + m*16 + j;
        if (col >= 320 && col < 448)      etile[rl*128 + (col - 320)] = acc[m][n][j];
        else if (col >= 448 && col < 452) stile[rl*8 + (col - 448)] = acc[m][n][j];
      }
    }
  // e.e partials (unchanged reduction chain)
  #pragma unroll
  for (int m = 0; m < 2; m++)
    #pragma unroll
    for (int j = 0; j < 4; j++){
      float p = 0.f;
      #pragma unroll
      for (int n = 0; n < 8; n++)
        if (wcol*128 + n*16 < 320){ float t = acc[m][n][j]; p += t*t; }
      #pragma unroll
      for (int off = 1; off < 16; off <<= 1) p += __shfl_xor(p, off);
      if ((lane & 15) == 0 && wcol < 3) e2part[wcol][rloc + m*16 + j] = p;
    }
  __syncthreads();
  if (tid < 64){
    stile[tid*8 + 4] = e2part[0][tid] + e2part[1][tid] + e2part[2][tid];
    stile[tid*8 + 5] = 0.f; stile[tid*8 + 6] = 0.f; stile[tid*8 + 7] = 0.f;
  }
  __syncthreads();
  // coalesced contiguous copy-out (EtT rows are dense: tile = linear 32 KB span)
  int nrow = NV - rowbase; if (nrow > 64) nrow = 64;
  float4* edst = (float4*)(EtT + (size_t)rowbase*128);
  const float4* esrc = (const float4*)etile;
  int e4 = nrow*32;
  for (int i = tid; i < e4; i += 512) edst[i] = esrc[i];
  float4* sdst = (float4*)(ETS + (size_t)rowbase*8);
  const float4* ssrc = (const float4*)stile;
  int s4 = nrow*2;
  for (int i = tid; i < s4; i += 512) sdst[i] = ssrc[i];
}

// ================= K45A: stats+softmax, gather own 128 tokens (4 blocks/b) =================
__global__ __launch_bounds__(512) void k45a(
    const int* __restrict__ sentence, const float* __restrict__ alpha,
    const float* __restrict__ scale_p, const float* __restrict__ embed,
    const float* __restrict__ EtT, const float* __restrict__ ETS,
    const float* __restrict__ BC, float* __restrict__ SBB, float* __restrict__ PRT)
{
  int bid = blockIdx.x;
  int b = bid >> 2, hb = bid & 3;
  int tid = threadIdx.x, lane = tid & 63, w = tid >> 6;
  __shared__ float red[512];
  __shared__ float cfs[NS*3];
  __shared__ int toksh[NS];
  __shared__ float cap8[8][3][CP];

  int idx = (b << 9) + tid;
  int tok = sentence[idx];
  float al = alpha[idx];
  toksh[tid] = tok;
  float et = EtT[(size_t)tok*128 + b];
  float4 eg = *(const float4*)(ETS + (size_t)tok*8);   // g0,g1,g2,ebs
  float e2 = ETS[(size_t)tok*8 + 4];
  float bst = BC[b];
  float bsg0 = BC[128], bsg1 = BC[129], bsg2 = BC[130], bs2 = BC[131];

  float sq = al*al*e2 + 2.f*al*eg.w + bs2;
  float ssv = (sq/(1.f+sq))/sqrtf(sq + SQ_EPS);
  float scv = (tok != 0) ? ssv*(al*et + bst) : MASK_NEG;
  float u0 = ssv*(al*eg.x + bsg0);
  float u1 = ssv*(al*eg.y + bsg1);
  float u2 = ssv*(al*eg.z + bsg2);

  float m = bmax512(scv, red, tid);
  float e = expf(scv - m);
  float Z = bsum512(e, red, tid);
  float nw = e / Z;
  float mk = fmaxf(u0, fmaxf(u1, u2));
  float e0 = expf(u0-mk), e1 = expf(u1-mk), e2k = expf(u2-mk);
  float wf = nw * scale_p[0] / (e0+e1+e2k);
  float w0 = e0*wf, w1 = e1*wf, w2 = e2k*wf;
  float ssvA = ssv * al;
  cfs[tid*3+0] = w0*ssvA; cfs[tid*3+1] = w1*ssvA; cfs[tid*3+2] = w2*ssvA;
  float sb0 = bsum512(w0*ssv, red, tid);
  float sb1 = bsum512(w1*ssv, red, tid);
  float sb2 = bsum512(w2*ssv, red, tid);
  if (hb == 0 && tid == 0){ SBB[b*3+0] = sb0; SBB[b*3+1] = sb1; SBB[b*3+2] = sb2; }
  __syncthreads();

  // gather this quarter's 128 tokens: wave w handles 16
  f32x4 A0 = {0.f,0.f,0.f,0.f}, A1 = A0, A2 = A0, R0 = A0, R1 = A0, R2 = A0;
  int c0 = lane << 2;
  int c1 = 256 + (lane << 2);
  bool rem = lane < 11;
  int base = (hb << 7) + (w << 4);
  #pragma unroll 4
  for (int i = 0; i < 16; i++){
    int s = base + i;
    int t = toksh[s];
    const float* er = embed + (size_t)t*ND;
    float4 y = *(const float4*)(er + c0);
    float cf0 = cfs[s*3+0], cf1 = cfs[s*3+1], cf2 = cfs[s*3+2];
    f32x4 yv = {y.x, y.y, y.z, y.w};
    A0 += cf0*yv; A1 += cf1*yv; A2 += cf2*yv;
    if (rem){
      float4 y2 = *(const float4*)(er + c1);
      f32x4 y2v = {y2.x, y2.y, y2.z, y2.w};
      R0 += cf0*y2v; R1 += cf1*y2v; R2 += cf2*y2v;
    }
  }
  *(f32x4*)&cap8[w][0][c0] = A0;
  *(f32x4*)&cap8[w][1][c0] = A1;
  *(f32x4*)&cap8[w][2][c0] = A2;
  if (rem){
    *(f32x4*)&cap8[w][0][c1] = R0;
    *(f32x4*)&cap8[w][1][c1] = R1;
    *(f32x4*)&cap8[w][2][c1] = R2;
  }
  __syncthreads();
  for (int p = tid; p < 3*CP; p += 512){
    int k = p / CP, c = p - k*CP;
    float v = 0.f;
    if (c < 300){
      #pragma unroll
      for (int w8 = 0; w8 < 8; w8++) v += cap8[w8][k][c];
    }
    PRT[((size_t)bid*3 + k)*CP + c] = v;
  }
}

// ================= K45B: Q@Ws + sb*bs -> squash norms -> out =================
__global__ __launch_bounds__(512) void k45b(
    const float* __restrict__ PRT, const float* __restrict__ SBB,
    const float* __restrict__ bs, const float* __restrict__ Ws,
    float* __restrict__ out)
{
  int b = blockIdx.x, tid = threadIdx.x;
  __shared__ float Qs[3][CP];
  __shared__ float red[512];
  for (int p = tid; p < 3*CP; p += 512){
    int k = p / CP, c = p - k*CP;
    float v = 0.f;
    if (c < 300){
      #pragma unroll
      for (int ch = 0; ch < 4; ch++)
        v += PRT[((size_t)(4*b+ch)*3 + k)*CP + c];
    }
    Qs[k][c] = v;
  }
  __syncthreads();
  float v0 = 0.f, v1 = 0.f, v2 = 0.f;
  if (tid < NC){
    float a0=0.f,a1=0.f,a2=0.f,b0=0.f,b1=0.f,b2=0.f;
    for (int d = 0; d < 300; d += 2){
      float wA = Ws[d*NC + tid], wB = Ws[(d+1)*NC + tid];
      a0 += wA*Qs[0][d]; b0 += wB*Qs[0][d+1];
      a1 += wA*Qs[1][d]; b1 += wB*Qs[1][d+1];
      a2 += wA*Qs[2][d]; b2 += wB*Qs[2][d+1];
    }
    float bc = bs[tid];
    v0 = a0+b0 + SBB[b*3+0]*bc;
    v1 = a1+b1 + SBB[b*3+1]*bc;
    v2 = a2+b2 + SBB[b*3+2]*bc;
  }
  float s0 = bsum512(v0*v0, red, tid);
  float s1 = bsum512(v1*v1, red, tid);
  float s2 = bsum512(v2*v2, red, tid);
  if (tid == 0){
    out[b*3+0] = (s0/(1.f+s0))*sqrtf(s0)/sqrtf(s0 + SQ_EPS);
    out[b*3+1] = (s1/(1.f+s1))*sqrtf(s1)/sqrtf(s1 + SQ_EPS);
    out[b*3+2] = (s2/(1.f+s2))*sqrtf(s2)/sqrtf(s2 + SQ_EPS);
  }
}

extern "C" void kernel_launch(void* const* d_in, const int* in_sizes, int n_in,
                              void* d_out, int out_size, void* d_ws, size_t ws_size,
                              hipStream_t stream)
{
  (void)in_sizes; (void)n_in; (void)out_size; (void)ws_size;
  const int*   sentence = (const int*)d_in[0];
  const int*   aspect   = (const int*)d_in[1];
  const float* alpha    = (const float*)d_in[2];
  const float* embed    = (const float*)d_in[3];
  const float* Ws       = (const float*)d_in[4];
  const float* bs       = (const float*)d_in[5];
  const float* Wa       = (const float*)d_in[6];
  const float* ba       = (const float*)d_in[7];
  const float* Watt     = (const float*)d_in[8];
  const float* gcap     = (const float*)d_in[9];
  const float* gw       = (const float*)d_in[10];
  const float* scale    = (const float*)d_in[11];
  float* out = (float*)d_out;

  char* w = (char*)d_ws;
  auto alloc = [&](size_t bytes)->char*{
    char* p = w; w += (bytes + 255) & ~(size_t)255; return p;
  };
  unsigned short* WTC = (unsigned short*)alloc((size_t)512*KP*2);
  float* ZG  = (float*)alloc((size_t)128*KP*4);
  float* Z2P = (float*)alloc((size_t)20*128*4);
  float* TG  = (float*)alloc((size_t)132*KP*4);
  float* BC  = (float*)alloc(136*4);
  float* ETT = (float*)alloc((size_t)NV*128*4);
  float* ETS = (float*)alloc((size_t)NV*8*4);
  float* SBB = (float*)alloc(NB*3*4);
  float* PRT = (float*)alloc((size_t)512*3*CP*4);

  kA<<<50, 512, 0, stream>>>(Ws, Wa, ba, aspect, embed, gcap, gw, bs, WTC, ZG, Z2P, TG);
  kB<<<20, 512, 0, stream>>>(ZG, Z2P, Watt, TG);
  kC<<<21, 512, 0, stream>>>(TG, Ws, bs, WTC, BC);
  k1f<<<(NV + 63)/64, 512, 0, stream>>>(embed, WTC, ETT, ETS);
  k45a<<<512, 512, 0, stream>>>(sentence, alpha, scale, embed, ETT, ETS, BC, SBB, PRT);
  k45b<<<NB, 512, 0, stream>>>(PRT, SBB, bs, Ws, out);
}